// Round 3
// baseline (30673.993 us; speedup 1.0000x reference)
//
#include <hip/hip_runtime.h>
#include <cstdint>

// Problem constants (fixed by the reference file).
#define HID     1024
#define G4      4096      // 4*HID
#define NB      32        // batch
#define VOCABSZ 32000
#define MAXLEN  128

// Layer GEMM K-split: virtual K = 2048 (x-half then h-half), 16 chunks of 128.
constexpr int KS = 16;
constexpr int KC = 128;
constexpr int CB = 256;   // gate columns per block

// Pred GEMM: 32000 cols, 128 per block -> 250 blocks; K staged in 4 chunks of 256.
constexpr int PCB = 128;
constexpr int PKC = 256;

__device__ __forceinline__ float sigf(float x) { return 1.0f / (1.0f + expf(-x)); }

// ---------------------------------------------------------------------------
__global__ __launch_bounds__(256) void init_kernel(const int* __restrict__ sid_p,
                                                   int* __restrict__ tok,
                                                   int* __restrict__ out,
                                                   int* __restrict__ counters) {
  const int sid = sid_p[0];
  const int t = threadIdx.x;
  if (t < NB) { tok[t] = sid; out[t * MAXLEN] = sid; }
  for (int i = t; i < MAXLEN - 1; i += 256) counters[i] = 0;
}

// ---------------------------------------------------------------------------
// Partial gates: gates[b][n] += sum_k x[b][k]*W[n][k] over this block's K-chunk.
// grid = (16 col-blocks, 16 k-chunks), block = 256 threads.
// ks < 8  -> x-part (emb gather for layer0, or xsrc=h_{l-1}) against W_ih
// ks >= 8 -> h-part (hprev) against W_hh
__global__ __launch_bounds__(256) void layer_partial(
    const float* __restrict__ Wih, const float* __restrict__ Whh,
    const float* __restrict__ emb, const int* __restrict__ tok,
    const float* __restrict__ xsrc, const float* __restrict__ hprev,
    float* __restrict__ partial) {
  __shared__ __align__(16) float xs[NB][KC];   // 16 KB
  const int cb = blockIdx.x;
  const int ks = blockIdx.y;
  const int tid = threadIdx.x;
  const int kv0 = ks * KC;
  const bool ihpart = (kv0 < HID);
  const int k0 = ihpart ? kv0 : (kv0 - HID);
  const float* __restrict__ W = ihpart ? Wih : Whh;

  // Stage x window (32 x 128 floats) into LDS, float4 per iteration.
  for (int i = tid; i < NB * (KC / 4); i += 256) {
    const int b = i / (KC / 4);
    const int q = i % (KC / 4);
    const float* src;
    if (ihpart) {
      src = emb ? (emb + (size_t)tok[b] * HID) : (xsrc + (size_t)b * HID);
    } else {
      src = hprev + (size_t)b * HID;
    }
    reinterpret_cast<float4*>(&xs[b][0])[q] =
        reinterpret_cast<const float4*>(src + k0)[q];
  }
  __syncthreads();

  const int bg = tid >> 6;       // wave id -> batch group (8 b's)
  const int lane = tid & 63;     // column group (4 cols)
  const int nb = cb * CB + lane * 4;
  const float* __restrict__ w0 = W + (size_t)nb * HID + k0;

  float acc[4][8];
#pragma unroll
  for (int t = 0; t < 4; ++t)
#pragma unroll
    for (int bb = 0; bb < 8; ++bb) acc[t][bb] = 0.0f;

  for (int kk = 0; kk < KC; kk += 4) {
    float4 wv[4];
#pragma unroll
    for (int t = 0; t < 4; ++t)
      wv[t] = *reinterpret_cast<const float4*>(w0 + (size_t)t * HID + kk);
#pragma unroll
    for (int bb = 0; bb < 8; ++bb) {
      const float4 xv = *reinterpret_cast<const float4*>(&xs[bg * 8 + bb][kk]);
#pragma unroll
      for (int t = 0; t < 4; ++t) {
        acc[t][bb] += wv[t].x * xv.x + wv[t].y * xv.y +
                      wv[t].z * xv.z + wv[t].w * xv.w;
      }
    }
  }

#pragma unroll
  for (int bb = 0; bb < 8; ++bb) {
    const int b = bg * 8 + bb;
    float4 v = make_float4(acc[0][bb], acc[1][bb], acc[2][bb], acc[3][bb]);
    *reinterpret_cast<float4*>(&partial[((size_t)ks * NB + b) * G4 + nb]) = v;
  }
}

// ---------------------------------------------------------------------------
// Sum partials + biases, LSTM elementwise update of h,c (one layer).
// grid = 128, block = 256 -> one thread per (b, j).
__global__ __launch_bounds__(256) void lstm_reduce(
    const float* __restrict__ partial, const float* __restrict__ bih,
    const float* __restrict__ bhh, float* __restrict__ h, float* __restrict__ c) {
  const int idx = blockIdx.x * 256 + threadIdx.x;   // 0..32767
  const int b = idx >> 10;
  const int j = idx & 1023;

  float g[4];
#pragma unroll
  for (int gate = 0; gate < 4; ++gate) {
    const int n = gate * HID + j;
    float s = bih[n] + bhh[n];
    for (int ks = 0; ks < KS; ++ks)
      s += partial[((size_t)ks * NB + b) * G4 + n];
    g[gate] = s;
  }
  const float ig = sigf(g[0]);
  const float fg = sigf(g[1]);
  const float gg = tanhf(g[2]);
  const float og = sigf(g[3]);
  const float cn = fg * c[idx] + ig * gg;
  const float hn = og * tanhf(cn);
  c[idx] = cn;
  h[idx] = hn;
}

// ---------------------------------------------------------------------------
// logits = h1 @ W_pred^T + b_pred; per-block argmax partials; last finishing
// block reduces partials, writes tok[] and out[:, step].
// grid = 250, block = 256.
__global__ __launch_bounds__(256) void pred_argmax(
    const float* __restrict__ Wp, const float* __restrict__ bp,
    const float* __restrict__ h1, unsigned long long* __restrict__ part,
    int* __restrict__ counter, int* __restrict__ tok, int* __restrict__ out,
    int step) {
  __shared__ __align__(16) float hs[NB][PKC];   // 32 KB
  const int cb = blockIdx.x;
  const int tid = threadIdx.x;
  const int bg = tid >> 6;
  const int lane = tid & 63;
  const int nb = cb * PCB + lane * 2;

  float acc[2][8];
#pragma unroll
  for (int t = 0; t < 2; ++t)
#pragma unroll
    for (int bb = 0; bb < 8; ++bb) acc[t][bb] = 0.0f;

  for (int ph = 0; ph < 4; ++ph) {
    const int k0 = ph * PKC;
    __syncthreads();
    for (int i = tid; i < NB * (PKC / 4); i += 256) {
      const int b = i / (PKC / 4);
      const int q = i % (PKC / 4);
      reinterpret_cast<float4*>(&hs[b][0])[q] =
          reinterpret_cast<const float4*>(h1 + (size_t)b * HID + k0)[q];
    }
    __syncthreads();
    const float* __restrict__ w0 = Wp + (size_t)nb * HID + k0;
    for (int kk = 0; kk < PKC; kk += 4) {
      const float4 wv0 = *reinterpret_cast<const float4*>(w0 + kk);
      const float4 wv1 = *reinterpret_cast<const float4*>(w0 + HID + kk);
#pragma unroll
      for (int bb = 0; bb < 8; ++bb) {
        const float4 xv = *reinterpret_cast<const float4*>(&hs[bg * 8 + bb][kk]);
        acc[0][bb] += wv0.x * xv.x + wv0.y * xv.y + wv0.z * xv.z + wv0.w * xv.w;
        acc[1][bb] += wv1.x * xv.x + wv1.y * xv.y + wv1.z * xv.z + wv1.w * xv.w;
      }
    }
  }

  const float bv0 = bp[nb];
  const float bv1 = bp[nb + 1];
  float bestv[8];
  int besti[8];
#pragma unroll
  for (int bb = 0; bb < 8; ++bb) {
    const float v0 = acc[0][bb] + bv0;
    const float v1 = acc[1][bb] + bv1;
    if (v0 >= v1) { bestv[bb] = v0; besti[bb] = nb; }      // tie -> lower idx
    else          { bestv[bb] = v1; besti[bb] = nb + 1; }
  }
  // Butterfly reduce across the 64 lanes of this wave (all same batch group).
#pragma unroll
  for (int off = 32; off; off >>= 1) {
#pragma unroll
    for (int bb = 0; bb < 8; ++bb) {
      const float ov = __shfl_xor(bestv[bb], off, 64);
      const int oi = __shfl_xor(besti[bb], off, 64);
      if (ov > bestv[bb] || (ov == bestv[bb] && oi < besti[bb])) {
        bestv[bb] = ov;
        besti[bb] = oi;
      }
    }
  }
  if (lane == 0) {
#pragma unroll
    for (int bb = 0; bb < 8; ++bb) {
      const unsigned long long p =
          ((unsigned long long)__float_as_uint(bestv[bb]) << 32) |
          (unsigned int)besti[bb];
      __hip_atomic_store(&part[(size_t)cb * NB + bg * 8 + bb], p,
                         __ATOMIC_RELEASE, __HIP_MEMORY_SCOPE_AGENT);
    }
  }
  __threadfence();
  __syncthreads();

  __shared__ int isLast;
  if (tid == 0) {
    const int old = atomicAdd(counter, 1);
    isLast = (old == (int)gridDim.x - 1);
  }
  __syncthreads();

  if (isLast) {
    __threadfence();
    const int b = tid >> 3;     // 0..31
    const int s = tid & 7;      // 8 scanners per b
    float bv = -3.4e38f;
    int bi = 0x7fffffff;
    for (int c2 = s; c2 < 250; c2 += 8) {
      const unsigned long long p = __hip_atomic_load(
          &part[(size_t)c2 * NB + b], __ATOMIC_ACQUIRE, __HIP_MEMORY_SCOPE_AGENT);
      const float v = __uint_as_float((unsigned int)(p >> 32));
      const int idx = (int)(unsigned int)(p & 0xffffffffu);
      if (v > bv || (v == bv && idx < bi)) { bv = v; bi = idx; }
    }
#pragma unroll
    for (int off = 4; off; off >>= 1) {
      const float ov = __shfl_xor(bv, off, 64);
      const int oi = __shfl_xor(bi, off, 64);
      if (ov > bv || (ov == bv && oi < bi)) { bv = ov; bi = oi; }
    }
    if (s == 0) {
      tok[b] = bi;
      out[b * MAXLEN + step] = bi;
    }
  }
}

// ---------------------------------------------------------------------------
extern "C" void kernel_launch(void* const* d_in, const int* in_sizes, int n_in,
                              void* d_out, int out_size, void* d_ws, size_t ws_size,
                              hipStream_t stream) {
  const float* hidden = (const float*)d_in[0];   // (2,32,1024)
  const float* cell   = (const float*)d_in[1];   // (2,32,1024)
  const float* emb    = (const float*)d_in[2];   // (32000,1024)
  const float* Wih    = (const float*)d_in[3];   // (2,4096,1024)
  const float* Whh    = (const float*)d_in[4];   // (2,4096,1024)
  const float* bih    = (const float*)d_in[5];   // (2,4096)
  const float* bhh    = (const float*)d_in[6];   // (2,4096)
  const float* Wp     = (const float*)d_in[7];   // (32000,1024)
  const float* bp     = (const float*)d_in[8];   // (32000,)
  const int*   sid    = (const int*)d_in[10];    // scalar
  int* out = (int*)d_out;                        // (32,128) int32

  char* ws = (char*)d_ws;
  float* h = (float*)ws;                         // (2,32,1024)
  float* c = h + 2 * NB * HID;                   // (2,32,1024)
  float* partial = c + 2 * NB * HID;             // (16,32,4096)
  unsigned long long* ppart =
      (unsigned long long*)(partial + (size_t)KS * NB * G4);  // (250,32)
  int* tok = (int*)(ppart + 250 * NB);
  int* counters = tok + NB;                      // (127,)

  hipMemcpyAsync(h, hidden, 2 * NB * HID * sizeof(float),
                 hipMemcpyDeviceToDevice, stream);
  hipMemcpyAsync(c, cell, 2 * NB * HID * sizeof(float),
                 hipMemcpyDeviceToDevice, stream);
  init_kernel<<<1, 256, 0, stream>>>(sid, tok, out, counters);

  const size_t loff = (size_t)G4 * HID;  // per-layer weight stride
  float* h0 = h;
  float* h1 = h + NB * HID;
  float* c0 = c;
  float* c1 = c + NB * HID;

  for (int step = 1; step < MAXLEN; ++step) {
    // Layer 0: x = emb[tok]
    layer_partial<<<dim3(16, 16), 256, 0, stream>>>(
        Wih, Whh, emb, tok, nullptr, h0, partial);
    lstm_reduce<<<128, 256, 0, stream>>>(partial, bih, bhh, h0, c0);
    // Layer 1: x = h0 (new)
    layer_partial<<<dim3(16, 16), 256, 0, stream>>>(
        Wih + loff, Whh + loff, nullptr, tok, h0, h1, partial);
    lstm_reduce<<<128, 256, 0, stream>>>(partial, bih + G4, bhh + G4, h1, c1);
    // Prediction + argmax -> tok, out[:, step]
    pred_argmax<<<250, 256, 0, stream>>>(Wp, bp, h1, ppart,
                                         counters + (step - 1), tok, out, step);
  }
}

// Round 5
// 21558.521 us; speedup vs baseline: 1.4228x; 1.4228x over previous
//
#include <hip/hip_runtime.h>
#include <cstdint>

#define HID     1024
#define G4      4096
#define NB      32
#define VOCABSZ 32000
#define MAXLEN  128

constexpr int KS  = 16;             // layer k-chunks over virtual K=2048
constexpr int KC  = 128;            // k per chunk
constexpr int LRB = 256;            // layer rows per block
constexpr int NLB = G4 / LRB;       // 16 row-blocks
constexpr int PROWS = 128;          // pred rows per block
constexpr int NPB = VOCABSZ / PROWS;  // 250
constexpr int PKC = 256;            // pred k per phase (4 phases)

__device__ __forceinline__ float sigf(float x) { return 1.0f / (1.0f + expf(-x)); }

// ---------------------------------------------------------------------------
__global__ __launch_bounds__(256) void init_kernel(const int* __restrict__ sid_p,
                                                   int* __restrict__ tok,
                                                   int* __restrict__ out,
                                                   int* __restrict__ counters) {
  const int sid = sid_p[0];
  const int t = threadIdx.x;
  if (t < NB) { tok[t] = sid; out[t * MAXLEN] = sid; }
  for (int i = t; i < MAXLEN - 1; i += 256) counters[i] = 0;
}

// ---------------------------------------------------------------------------
// Layer gate partials. grid = (16 row-blocks, 16 k-chunks), 256 threads.
// Wave = 16 row-groups x 4 k-lanes; each lane owns 4 consecutive rows.
// Coalesced W reads: 16 lines/instruction. x staged in LDS (broadcast reads).
__global__ __launch_bounds__(256, 1) void layer_partial(
    const float* __restrict__ Wih, const float* __restrict__ Whh,
    const float* __restrict__ emb, const int* __restrict__ tok,
    const float* __restrict__ xsrc, const float* __restrict__ hprev,
    float* __restrict__ partial) {
  __shared__ __align__(16) float xs[NB][KC];   // 16 KB
  const int cb = blockIdx.x;        // row-block 0..15
  const int ks = blockIdx.y;        // k-chunk  0..15
  const int tid = threadIdx.x;
  const int kv0 = ks * KC;
  const bool ihpart = (kv0 < HID);
  const int k0 = ihpart ? kv0 : (kv0 - HID);
  const float* __restrict__ W = ihpart ? Wih : Whh;

  for (int i = tid; i < NB * (KC / 4); i += 256) {
    const int b = i >> 5;           // KC/4 = 32
    const int q = i & 31;
    const float* src = ihpart ? (emb ? emb + (size_t)tok[b] * HID
                                     : xsrc + (size_t)b * HID)
                              : hprev + (size_t)b * HID;
    reinterpret_cast<float4*>(&xs[b][0])[q] =
        reinterpret_cast<const float4*>(src + k0)[q];
  }
  __syncthreads();

  const int w = tid >> 6, l = tid & 63;
  const int g = l >> 2;             // row-group 0..15
  const int j = l & 3;              // k-lane 0..3
  const int r0 = cb * LRB + w * 64 + g * 4;   // 4 consecutive rows per lane
  const float* __restrict__ wp = W + (size_t)r0 * HID + k0;

  float a0[NB], a1[NB], a2[NB], a3[NB];
#pragma unroll
  for (int b = 0; b < NB; ++b) { a0[b] = 0.f; a1[b] = 0.f; a2[b] = 0.f; a3[b] = 0.f; }

#pragma unroll 2
  for (int kk = 0; kk < KC / 16; ++kk) {      // 8 iters, 16 k per iter
    const int kl = kk * 16 + j * 4;
    const float4 w0 = *reinterpret_cast<const float4*>(wp + kl);
    const float4 w1 = *reinterpret_cast<const float4*>(wp + HID + kl);
    const float4 w2 = *reinterpret_cast<const float4*>(wp + 2 * HID + kl);
    const float4 w3 = *reinterpret_cast<const float4*>(wp + 3 * HID + kl);
#pragma unroll
    for (int b = 0; b < NB; ++b) {
      const float4 xv = *reinterpret_cast<const float4*>(&xs[b][kl]);
      a0[b] += w0.x * xv.x + w0.y * xv.y + w0.z * xv.z + w0.w * xv.w;
      a1[b] += w1.x * xv.x + w1.y * xv.y + w1.z * xv.z + w1.w * xv.w;
      a2[b] += w2.x * xv.x + w2.y * xv.y + w2.z * xv.z + w2.w * xv.w;
      a3[b] += w3.x * xv.x + w3.y * xv.y + w3.z * xv.z + w3.w * xv.w;
    }
  }
  // Sum the 4 k-lane slices (butterfly over lanes l^1, l^2).
#pragma unroll
  for (int off = 1; off <= 2; off <<= 1) {
#pragma unroll
    for (int b = 0; b < NB; ++b) {
      a0[b] += __shfl_xor(a0[b], off, 64);
      a1[b] += __shfl_xor(a1[b], off, 64);
      a2[b] += __shfl_xor(a2[b], off, 64);
      a3[b] += __shfl_xor(a3[b], off, 64);
    }
  }
  // Lane j writes batches [j*8, j*8+8); rows r0..r0+3 are one float4 (aligned).
#define LWR(b) { float4 v = make_float4(a0[b], a1[b], a2[b], a3[b]); \
    *reinterpret_cast<float4*>(&partial[((size_t)ks * NB + (b)) * G4 + r0]) = v; }
  if (j == 0)      { LWR(0)  LWR(1)  LWR(2)  LWR(3)  LWR(4)  LWR(5)  LWR(6)  LWR(7)  }
  else if (j == 1) { LWR(8)  LWR(9)  LWR(10) LWR(11) LWR(12) LWR(13) LWR(14) LWR(15) }
  else if (j == 2) { LWR(16) LWR(17) LWR(18) LWR(19) LWR(20) LWR(21) LWR(22) LWR(23) }
  else             { LWR(24) LWR(25) LWR(26) LWR(27) LWR(28) LWR(29) LWR(30) LWR(31) }
#undef LWR
}

// ---------------------------------------------------------------------------
// Sum partials + biases, LSTM elementwise update. grid = 256 x 128 threads.
__global__ __launch_bounds__(128) void lstm_reduce(
    const float* __restrict__ partial, const float* __restrict__ bih,
    const float* __restrict__ bhh, float* __restrict__ h, float* __restrict__ c) {
  const int idx = blockIdx.x * 128 + threadIdx.x;   // 0..32767
  const int b = idx >> 10;
  const int jj = idx & 1023;

  float g[4];
#pragma unroll
  for (int gate = 0; gate < 4; ++gate) {
    const int n = gate * HID + jj;
    float s = bih[n] + bhh[n];
#pragma unroll
    for (int ks2 = 0; ks2 < KS; ++ks2)
      s += partial[((size_t)ks2 * NB + b) * G4 + n];
    g[gate] = s;
  }
  const float ig = sigf(g[0]);
  const float fg = sigf(g[1]);
  const float gg = tanhf(g[2]);
  const float og = sigf(g[3]);
  const float cn = fg * c[idx] + ig * gg;
  const float hn = og * tanhf(cn);
  c[idx] = cn;
  h[idx] = hn;
}

// ---------------------------------------------------------------------------
// logits = h1 @ Wp^T + bp, fused argmax. grid = 250, 256 threads.
// Wave = 8 row-groups x 8 k-lanes; each lane owns 4 consecutive rows.
__global__ __launch_bounds__(256, 1) void pred_argmax(
    const float* __restrict__ Wp, const float* __restrict__ bp,
    const float* __restrict__ h1, unsigned long long* __restrict__ part,
    int* __restrict__ counter, int* __restrict__ tok, int* __restrict__ out,
    int step) {
  __shared__ __align__(16) float xs[NB][PKC];   // 32 KB
  __shared__ float swv[4][NB];
  __shared__ int   swi[4][NB];
  const int cb = blockIdx.x;
  const int tid = threadIdx.x;
  const int w = tid >> 6, l = tid & 63;
  const int g = l >> 3;             // row-group 0..7
  const int j = l & 7;              // k-lane 0..7
  const int r0 = cb * PROWS + w * 32 + g * 4;

  float a0[NB], a1[NB], a2[NB], a3[NB];
#pragma unroll
  for (int b = 0; b < NB; ++b) { a0[b] = 0.f; a1[b] = 0.f; a2[b] = 0.f; a3[b] = 0.f; }

  for (int ph = 0; ph < 4; ++ph) {
    const int k0 = ph * PKC;
    __syncthreads();
    for (int i = tid; i < NB * (PKC / 4); i += 256) {
      const int b = i >> 6;         // PKC/4 = 64
      const int q = i & 63;
      reinterpret_cast<float4*>(&xs[b][0])[q] =
          reinterpret_cast<const float4*>(h1 + (size_t)b * HID + k0)[q];
    }
    __syncthreads();
    const float* __restrict__ wp = Wp + (size_t)r0 * HID + k0;
#pragma unroll 2
    for (int kk = 0; kk < PKC / 32; ++kk) {   // 8 iters, 32 k per iter
      const int kl = kk * 32 + j * 4;
      const float4 w0 = *reinterpret_cast<const float4*>(wp + kl);
      const float4 w1 = *reinterpret_cast<const float4*>(wp + HID + kl);
      const float4 w2 = *reinterpret_cast<const float4*>(wp + 2 * HID + kl);
      const float4 w3 = *reinterpret_cast<const float4*>(wp + 3 * HID + kl);
#pragma unroll
      for (int b = 0; b < NB; ++b) {
        const float4 xv = *reinterpret_cast<const float4*>(&xs[b][kl]);
        a0[b] += w0.x * xv.x + w0.y * xv.y + w0.z * xv.z + w0.w * xv.w;
        a1[b] += w1.x * xv.x + w1.y * xv.y + w1.z * xv.z + w1.w * xv.w;
        a2[b] += w2.x * xv.x + w2.y * xv.y + w2.z * xv.z + w2.w * xv.w;
        a3[b] += w3.x * xv.x + w3.y * xv.y + w3.z * xv.z + w3.w * xv.w;
      }
    }
  }
  // Sum the 8 k-lane slices.
#pragma unroll
  for (int off = 1; off <= 4; off <<= 1) {
#pragma unroll
    for (int b = 0; b < NB; ++b) {
      a0[b] += __shfl_xor(a0[b], off, 64);
      a1[b] += __shfl_xor(a1[b], off, 64);
      a2[b] += __shfl_xor(a2[b], off, 64);
      a3[b] += __shfl_xor(a3[b], off, 64);
    }
  }
  // Bias + per-lane argmax over 4 rows (ascending t, strict > => lowest idx).
  const float bv0 = bp[r0], bv1 = bp[r0 + 1], bv2 = bp[r0 + 2], bv3 = bp[r0 + 3];
  float bestv[NB]; int besti[NB];
#pragma unroll
  for (int b = 0; b < NB; ++b) {
    float v = a0[b] + bv0; int bi = r0;
    const float t1 = a1[b] + bv1; if (t1 > v) { v = t1; bi = r0 + 1; }
    const float t2 = a2[b] + bv2; if (t2 > v) { v = t2; bi = r0 + 2; }
    const float t3 = a3[b] + bv3; if (t3 > v) { v = t3; bi = r0 + 3; }
    bestv[b] = v; besti[b] = bi;
  }
  // Reduce over the 8 row-groups (k-lane duplicates identical; offs 8,16,32).
#pragma unroll
  for (int off = 8; off <= 32; off <<= 1) {
#pragma unroll
    for (int b = 0; b < NB; ++b) {
      const float ov = __shfl_xor(bestv[b], off, 64);
      const int oi = __shfl_xor(besti[b], off, 64);
      if (ov > bestv[b] || (ov == bestv[b] && oi < besti[b])) {
        bestv[b] = ov; besti[b] = oi;
      }
    }
  }
  if (l == 0) {
#pragma unroll
    for (int b = 0; b < NB; ++b) { swv[w][b] = bestv[b]; swi[w][b] = besti[b]; }
  }
  __syncthreads();
  if (tid < NB) {
    float bv = swv[0][tid]; int bi = swi[0][tid];
#pragma unroll
    for (int ww = 1; ww < 4; ++ww) {
      const float ov = swv[ww][tid]; const int oi = swi[ww][tid];
      if (ov > bv || (ov == bv && oi < bi)) { bv = ov; bi = oi; }
    }
    const unsigned long long p =
        ((unsigned long long)__float_as_uint(bv) << 32) | (unsigned int)bi;
    __hip_atomic_store(&part[(size_t)cb * NB + tid], p,
                       __ATOMIC_RELEASE, __HIP_MEMORY_SCOPE_AGENT);
  }
  __threadfence();
  __syncthreads();

  __shared__ int isLast;
  if (tid == 0) isLast = (atomicAdd(counter, 1) == NPB - 1);
  __syncthreads();

  if (isLast) {
    __threadfence();
    const int b = tid >> 3;       // 0..31
    const int s = tid & 7;        // 8 scanners per batch
    float bv = -3.4e38f;
    int bi = 0x7fffffff;
    for (int c2 = s; c2 < NPB; c2 += 8) {
      const unsigned long long p = __hip_atomic_load(
          &part[(size_t)c2 * NB + b], __ATOMIC_ACQUIRE, __HIP_MEMORY_SCOPE_AGENT);
      const float v = __uint_as_float((unsigned int)(p >> 32));
      const int i2 = (int)(unsigned int)(p & 0xffffffffu);
      if (v > bv || (v == bv && i2 < bi)) { bv = v; bi = i2; }
    }
#pragma unroll
    for (int off = 4; off; off >>= 1) {
      const float ov = __shfl_xor(bv, off, 64);
      const int oi = __shfl_xor(bi, off, 64);
      if (ov > bv || (ov == bv && oi < bi)) { bv = ov; bi = oi; }
    }
    if (s == 0) {
      tok[b] = bi;
      out[b * MAXLEN + step] = bi;
    }
  }
}

// ---------------------------------------------------------------------------
extern "C" void kernel_launch(void* const* d_in, const int* in_sizes, int n_in,
                              void* d_out, int out_size, void* d_ws, size_t ws_size,
                              hipStream_t stream) {
  const float* hidden = (const float*)d_in[0];   // (2,32,1024)
  const float* cell   = (const float*)d_in[1];   // (2,32,1024)
  const float* emb    = (const float*)d_in[2];   // (32000,1024)
  const float* Wih    = (const float*)d_in[3];   // (2,4096,1024)
  const float* Whh    = (const float*)d_in[4];   // (2,4096,1024)
  const float* bih    = (const float*)d_in[5];   // (2,4096)
  const float* bhh    = (const float*)d_in[6];   // (2,4096)
  const float* Wp     = (const float*)d_in[7];   // (32000,1024)
  const float* bp     = (const float*)d_in[8];   // (32000,)
  const int*   sid    = (const int*)d_in[10];    // scalar
  int* out = (int*)d_out;                        // (32,128) int32

  char* ws = (char*)d_ws;
  float* h = (float*)ws;                         // (2,32,1024)
  float* c = h + 2 * NB * HID;                   // (2,32,1024)
  float* partial = c + 2 * NB * HID;             // (16,32,4096)
  unsigned long long* ppart =
      (unsigned long long*)(partial + (size_t)KS * NB * G4);  // (250,32)
  int* tok = (int*)(ppart + (size_t)NPB * NB);
  int* counters = tok + NB;                      // (127,)

  hipMemcpyAsync(h, hidden, 2 * NB * HID * sizeof(float),
                 hipMemcpyDeviceToDevice, stream);
  hipMemcpyAsync(c, cell, 2 * NB * HID * sizeof(float),
                 hipMemcpyDeviceToDevice, stream);
  init_kernel<<<1, 256, 0, stream>>>(sid, tok, out, counters);

  const size_t loff = (size_t)G4 * HID;  // per-layer weight stride
  float* h0 = h;
  float* h1 = h + NB * HID;
  float* c0 = c;
  float* c1 = c + NB * HID;

  for (int step = 1; step < MAXLEN; ++step) {
    // Layer 0: x = emb[tok]
    layer_partial<<<dim3(NLB, KS), 256, 0, stream>>>(
        Wih, Whh, emb, tok, nullptr, h0, partial);
    lstm_reduce<<<256, 128, 0, stream>>>(partial, bih, bhh, h0, c0);
    // Layer 1: x = h0 (new)
    layer_partial<<<dim3(NLB, KS), 256, 0, stream>>>(
        Wih + loff, Whh + loff, nullptr, tok, h0, h1, partial);
    lstm_reduce<<<256, 128, 0, stream>>>(partial, bih + G4, bhh + G4, h1, c1);
    // Prediction + argmax -> tok, out[:, step]
    pred_argmax<<<NPB, 256, 0, stream>>>(Wp, bp, h1, ppart,
                                         counters + (step - 1), tok, out, step);
  }
}